// Round 21
// baseline (143.953 us; speedup 1.0000x reference)
//
#include <hip/hip_runtime.h>
#include <hip/hip_bf16.h>
#include <stdint.h>

#define NSEQ 4096
#define DDIM 512
#define NB   8
#define FN   8192          // FFT length = 2*NSEQ

#define PADI(i) ((i) + ((i) >> 4))

struct __align__(8) cf { float x, y; };

__device__ __forceinline__ cf cadd(cf a, cf b) { return {a.x + b.x, a.y + b.y}; }
__device__ __forceinline__ cf csub(cf a, cf b) { return {a.x - b.x, a.y - b.y}; }
__device__ __forceinline__ cf cmul(cf a, cf b) {
    return {a.x * b.x - a.y * b.y, a.x * b.y + a.y * b.x};
}
__device__ __forceinline__ cf cmulc(cf a, cf b) {   // a * conj(b)
    return {a.x * b.x + a.y * b.y, a.y * b.x - a.x * b.y};
}
template<int DIR> __device__ __forceinline__ cf crot(cf z) {  // *(-i) fwd, *(+i) inv
    return DIR < 0 ? cf{z.y, -z.x} : cf{-z.y, z.x};
}

__device__ __forceinline__ unsigned short f2bf(float f) {
    union { float f; unsigned int u; } v;
    v.f = f;
    unsigned int u = v.u;
    u += 0x7FFFu + ((u >> 16) & 1u);   // RNE
    return (unsigned short)(u >> 16);
}
__device__ __forceinline__ float bf2f(unsigned short u) {
    union { unsigned int i; float f; } v;
    v.i = (unsigned int)u << 16;
    return v.f;
}

// ---------------------------------------------------------------------------
// 8-point DFT pieces
// ---------------------------------------------------------------------------
template<int DIR>
__device__ __forceinline__ void fft4(cf& b0, cf& b1, cf& b2, cf& b3) {
    cf s0 = cadd(b0, b2), s1 = csub(b0, b2);
    cf s2 = cadd(b1, b3), s3 = crot<DIR>(csub(b1, b3));
    b0 = cadd(s0, s2); b1 = cadd(s1, s3);
    b2 = csub(s0, s2); b3 = csub(s1, s3);
}

template<int DIR>
__device__ __forceinline__ void dft8(cf a[8]) {
    cf e0 = a[0], e1 = a[2], e2 = a[4], e3 = a[6];
    cf o0 = a[1], o1 = a[3], o2 = a[5], o3 = a[7];
    fft4<DIR>(e0, e1, e2, e3);
    fft4<DIR>(o0, o1, o2, o3);
    const float c = 0.70710678118654752f;
    cf w1 = (DIR < 0) ? cf{c, -c} : cf{c, c};
    cf w3 = (DIR < 0) ? cf{-c, -c} : cf{-c, c};
    o1 = cmul(o1, w1);
    o2 = crot<DIR>(o2);
    o3 = cmul(o3, w3);
    a[0] = cadd(e0, o0); a[1] = cadd(e1, o1); a[2] = cadd(e2, o2); a[3] = cadd(e3, o3);
    a[4] = csub(e0, o0); a[5] = csub(e1, o1); a[6] = csub(e2, o2); a[7] = csub(e3, o3);
}

// DFT8 with a[4..7] == 0 (zero-padded upper half), inputs a0..a3
template<int DIR>
__device__ __forceinline__ void dft8_half(cf a0, cf a1, cf a2, cf a3, cf a[8]) {
    cf r2 = crot<DIR>(a2), r3 = crot<DIR>(a3);
    cf e0 = cadd(a0, a2), e1 = cadd(a0, r2), e2 = csub(a0, a2), e3 = csub(a0, r2);
    cf o0 = cadd(a1, a3), o1 = cadd(a1, r3), o2 = csub(a1, a3), o3 = csub(a1, r3);
    const float c = 0.70710678118654752f;
    cf w1 = (DIR < 0) ? cf{c, -c} : cf{c, c};
    cf w3 = (DIR < 0) ? cf{-c, -c} : cf{-c, c};
    o1 = cmul(o1, w1);
    o2 = crot<DIR>(o2);
    o3 = cmul(o3, w3);
    a[0] = cadd(e0, o0); a[1] = cadd(e1, o1); a[2] = cadd(e2, o2); a[3] = cadd(e3, o3);
    a[4] = csub(e0, o0); a[5] = csub(e1, o1); a[6] = csub(e2, o2); a[7] = csub(e3, o3);
}

// depth-3 twiddle powers w[k] = w1^k, k=1..7
__device__ __forceinline__ void twpow(cf w1, cf w[8]) {
    w[1] = w1;
    w[2] = cmul(w1, w1);
    w[3] = cmul(w[2], w1);
    w[4] = cmul(w[2], w[2]);
    w[5] = cmul(w[4], w1);
    w[6] = cmul(w[4], w[2]);
    w[7] = cmul(w[4], w[3]);
}

// ---------------------------------------------------------------------------
// radix-8 stage with LDS power table W7[t8*7+k-1] = w(8*t8)^k.
// ONE butterfly per thread (1024 threads).  fwd: dft8 then *w^k ;
// inv: *conj(w^k) then dft8.
// ---------------------------------------------------------------------------
template<int DIR, int LM, int TMUL>
__device__ __forceinline__ void r8_stage_tab(cf* Z, const cf* W7, int tid) {
    const int m = 1 << LM;
    int j = tid & (m - 1);
    int g = tid >> LM;
    int base = (g << (LM + 3)) + j;
    cf a[8];
#pragma unroll
    for (int r = 0; r < 8; ++r) a[r] = Z[PADI(base + (r << LM))];
    cf w[8];
#pragma unroll
    for (int k = 1; k < 8; ++k) w[k] = W7[j * TMUL + k - 1];
    if (DIR > 0) {
#pragma unroll
        for (int k = 1; k < 8; ++k) a[k] = cmulc(a[k], w[k]);
    }
    dft8<DIR>(a);
    if (DIR < 0) {
#pragma unroll
        for (int k = 1; k < 8; ++k) a[k] = cmul(a[k], w[k]);
    }
#pragma unroll
    for (int r = 0; r < 8; ++r) Z[PADI(base + (r << LM))] = a[r];
}

// radix-2 stage on adjacent pairs (build_V only)
template<int NTHR>
__device__ __forceinline__ void r2_stage(cf* Z, int tid) {
#pragma unroll
    for (int q = 0; q < 4096 / NTHR; ++q) {
        int beta = q * NTHR + tid;
        int i0 = PADI(2 * beta), i1 = i0 + 1;
        cf a = Z[i0], b = Z[i1];
        Z[i0] = cadd(a, b);
        Z[i1] = csub(a, b);
    }
}

// sincos-based radix-8 stage (build_V only; runs once)
template<int DIR, int NTHR>
__device__ __forceinline__ void r8_stage(cf* Z, int lm, int tid) {
    const int m = 1 << lm;
    const float ang0 = ((DIR < 0) ? -6.2831853071795865f : 6.2831853071795865f)
                       / (float)(m * 8);
#pragma unroll
    for (int q = 0; q < 1024 / NTHR; ++q) {
        int beta = q * NTHR + tid;
        int j = beta & (m - 1);
        int g = beta >> lm;
        int base = (g << (lm + 3)) + j;
        cf a[8];
#pragma unroll
        for (int r = 0; r < 8; ++r) a[r] = Z[PADI(base + (r << lm))];
        float sn, cs;
        __sincosf(ang0 * (float)j, &sn, &cs);
        cf w[8];
        twpow({cs, sn}, w);
        if (DIR > 0) {
#pragma unroll
            for (int k = 1; k < 8; ++k) a[k] = cmul(a[k], w[k]);
        }
        dft8<DIR>(a);
        if (DIR < 0) {
#pragma unroll
            for (int k = 1; k < 8; ++k) a[k] = cmul(a[k], w[k]);
        }
#pragma unroll
        for (int r = 0; r < 8; ++r) Z[PADI(base + (r << lm))] = a[r];
    }
}

// ---------------------------------------------------------------------------
// Kernel 1 (fused prep): block 0 builds the FOLDED mid-table Vt; blocks
// 1..4096 transpose+convert x -> xT.  (radix-8 chain, matches fft_conv)
// ---------------------------------------------------------------------------
__global__ __launch_bounds__(512) void prep(const float* __restrict__ x,
                                            const float* __restrict__ pos,
                                            const float* __restrict__ zero,
                                            const float* __restrict__ neg,
                                            unsigned short* __restrict__ xT,
                                            float4* __restrict__ Vt4) {
    __shared__ cf Z[PADI(FN)];
    int tid = threadIdx.x;
    if (blockIdx.x == 0) {
        float zv = zero[0];
#pragma unroll
        for (int q = 0; q < 16; ++q) {
            int t = q * 512 + tid;
            float v;
            if (t == 0 || t == NSEQ) v = zv;
            else if (t < NSEQ)       v = pos[t - 1];
            else                     v = neg[t - NSEQ - 1];
            v = fminf(fmaxf(v, -60.0f), 30.0f);
            Z[PADI(t)] = {__expf(v), 0.0f};
        }
        __syncthreads();
        r8_stage<-1, 512>(Z, 10, tid); __syncthreads();
        r8_stage<-1, 512>(Z, 7,  tid); __syncthreads();
        r8_stage<-1, 512>(Z, 4,  tid); __syncthreads();
        r8_stage<-1, 512>(Z, 1,  tid); __syncthreads();
        r2_stage<512>(Z, tid);         __syncthreads();
        const float sc = 1.0f / (float)FN;
#pragma unroll
        for (int q = 0; q < 16; ++q) {
            int i = q * 512 + tid;
            int p = i >> 1, r = p & 7;
            cf V0 = Z[PADI(2 * p)], V1 = Z[PADI(2 * p + 1)];
            cf Vp = {(V0.x + V1.x) * sc, (V0.y + V1.y) * sc};
            cf Vm = {(V0.x - V1.x) * sc, (V0.y - V1.y) * sc};
            float sn, cs;
            __sincosf(-0.39269908169872415f * (float)r, &sn, &cs);
            cf wf = {cs, sn};
            cf B = (i & 1) ? cmulc(Vm, wf) : cmul(Vm, wf);
            Vt4[i] = {Vp.x, Vp.y, B.x, B.y};
        }
    } else {
        unsigned short (*tl)[72] = (unsigned short (*)[72])Z;   // alias LDS
        int t   = blockIdx.x - 1;
        int b   = t >> 9;
        int rem = t & 511;
        int j0  = (rem >> 3) << 6;
        int d0  = (rem & 7) << 6;
        const float* xb = x + (size_t)b * NSEQ * DDIM;
#pragma unroll
        for (int e = 0; e < 2; ++e) {
            int idx = e * 512 + tid;
            int r   = idx >> 4;
            int c4  = (idx & 15) << 2;
            float4 v = *(const float4*)&xb[(size_t)(j0 + r) * DDIM + d0 + c4];
            ushort4 o;
            o.x = f2bf(v.x); o.y = f2bf(v.y); o.z = f2bf(v.z); o.w = f2bf(v.w);
            *(ushort4*)&tl[r][c4] = o;
        }
        __syncthreads();
        unsigned short* xtb = xT + (size_t)b * DDIM * NSEQ;
#pragma unroll
        for (int e = 0; e < 2; ++e) {
            int idx = e * 512 + tid;
            int d   = idx >> 4;
            int jq  = (idx & 15) << 2;
            ushort4 o;
            o.x = tl[jq + 0][d]; o.y = tl[jq + 1][d];
            o.z = tl[jq + 2][d]; o.w = tl[jq + 3][d];
            *(ushort4*)&xtb[(size_t)(d0 + d) * NSEQ + j0 + jq] = o;
        }
    }
}

// ---------------------------------------------------------------------------
// Kernel 2: per column-pair FFT convolution — r18 radix-8 chain at 1024
// THREADS (one butterfly/thread/stage), 2 blocks/CU (LDS 80896 x2 <= 160K)
// -> 8 waves/SIMD for latency hiding.  __launch_bounds__(1024,8) pins 64
// VGPR (r18's measured need; single-butterfly body is lighter than r18's
// two interleaved).  Wt[512] + wave-uniform KF fixup for tid>=512.
// ---------------------------------------------------------------------------
__global__ __launch_bounds__(1024, 8) void fft_conv(unsigned short* __restrict__ xT,
                                                    const float4* __restrict__ Vt4) {
    __shared__ cf Z[PADI(FN)];
    __shared__ cf Wt[512];
    __shared__ cf W7[896];          // [t8][k-1] = w(8*t8)^k
    int tid = threadIdx.x;
    int blk = blockIdx.x;
    int b   = blk >> 8;
    int dp  = blk & 255;
    unsigned short* col0 = xT + ((size_t)(b * DDIM + 2 * dp)) * NSEQ;
    unsigned short* col1 = col0 + NSEQ;

    // ---- build tables ----
    {
        float sn, cs;
        if (tid < 512) {
            __sincosf(-7.66990393942820625e-04f * (float)tid, &sn, &cs);  // -2pi t/8192
            Wt[tid] = {cs, sn};
        }
        if (tid < 896) {
            int t8 = tid / 7, k = tid - t8 * 7 + 1;
            __sincosf(-6.13592315154256492e-03f * (float)(t8 * k), &sn, &cs); // -pi/512*t8*k
            W7[tid] = {cs, sn};
        }
    }
    __syncthreads();

    const cf KF = {0.92387953251128674f, -0.38268343236508977f};  // e^{-i pi/8}

    // ---- fused load + first forward stage (lm=10, half-zero) ----
    {
        int j = tid;
        cf a0 = {bf2f(col0[j]),        bf2f(col1[j])};
        cf a1 = {bf2f(col0[j + 1024]), bf2f(col1[j + 1024])};
        cf a2 = {bf2f(col0[j + 2048]), bf2f(col1[j + 2048])};
        cf a3 = {bf2f(col0[j + 3072]), bf2f(col1[j + 3072])};
        cf a[8];
        dft8_half<-1>(a0, a1, a2, a3, a);
        cf w1 = Wt[j & 511];
        if (j >> 9) w1 = cmul(w1, KF);       // wave-uniform branch
        cf w[8];
        twpow(w1, w);
#pragma unroll
        for (int k = 1; k < 8; ++k) a[k] = cmul(a[k], w[k]);
#pragma unroll
        for (int r = 0; r < 8; ++r) Z[PADI(j + (r << 10))] = a[r];
    }
    __syncthreads();

    r8_stage_tab<-1, 7, 7>(Z, W7, tid);   __syncthreads();
    r8_stage_tab<-1, 4, 56>(Z, W7, tid);  __syncthreads();

    // ---- merged: fwd lm=1 + R2 diag(V) R2 + inv lm=1 (twiddles folded) ----
    {
        const int g  = tid >> 1;
        const int jj = tid & 1;
        const int base = g * 16 + jj;
        cf a[8];
#pragma unroll
        for (int r = 0; r < 8; ++r) a[r] = Z[PADI(base + 2 * r)];
        dft8<-1>(a);
#pragma unroll
        for (int r = 0; r < 8; ++r) {
            cf own = a[r];
            cf oth;
            oth.x = __shfl_xor(own.x, 1);
            oth.y = __shfl_xor(own.y, 1);
            float4 v = Vt4[base + 2 * r];
            a[r] = cadd(cmul({v.x, v.y}, own), cmul({v.z, v.w}, oth));
        }
        dft8<1>(a);
#pragma unroll
        for (int r = 0; r < 8; ++r) Z[PADI(base + 2 * r)] = a[r];
    }
    __syncthreads();

    r8_stage_tab<1, 4, 56>(Z, W7, tid);   __syncthreads();
    r8_stage_tab<1, 7, 7>(Z, W7, tid);    __syncthreads();

    // ---- fused last inverse stage (lm=10) + store (only idx < 4096) ----
    {
        int j = tid;
        cf a[8];
#pragma unroll
        for (int r = 0; r < 8; ++r) a[r] = Z[PADI(j + (r << 10))];
        cf w1 = Wt[j & 511];
        if (j >> 9) w1 = cmul(w1, KF);
        w1.y = -w1.y;                       // conjugate for inverse
        cf w[8];
        twpow(w1, w);
#pragma unroll
        for (int k = 1; k < 8; ++k) a[k] = cmul(a[k], w[k]);
        dft8<1>(a);
#pragma unroll
        for (int r = 0; r < 4; ++r) {
            col0[j + (r << 10)] = f2bf(a[r].x);
            col1[j + (r << 10)] = f2bf(a[r].y);
        }
    }
}

// ---------------------------------------------------------------------------
// Kernel 3: un-transpose  out[b][j][d] = f32(outT[b][d][j]).  grid (64,8,8).
// ---------------------------------------------------------------------------
__global__ void untranspose(const unsigned short* __restrict__ oT,
                            float* __restrict__ out) {
    __shared__ unsigned short tl[64][65];
    int j0 = blockIdx.x * 64, d0 = blockIdx.y * 64, b = blockIdx.z;
    const unsigned short* src = oT + (size_t)b * DDIM * NSEQ;
#pragma unroll
    for (int e = 0; e < 16; ++e) {
        int idx = e * 256 + threadIdx.x;
        int r = idx >> 6, c = idx & 63;
        tl[r][c] = src[(size_t)(d0 + r) * NSEQ + j0 + c];
    }
    __syncthreads();
    float* dst = out + ((size_t)b * NSEQ + j0) * DDIM + d0;
#pragma unroll
    for (int e = 0; e < 16; ++e) {
        int idx = e * 256 + threadIdx.x;
        int r = idx >> 6, c = idx & 63;
        dst[(size_t)r * DDIM + c] = bf2f(tl[c][r]);
    }
}

// ---------------------------------------------------------------------------
extern "C" void kernel_launch(void* const* d_in, const int* in_sizes, int n_in,
                              void* d_out, int out_size, void* d_ws, size_t ws_size,
                              hipStream_t stream) {
    const float* x    = (const float*)d_in[0];
    const float* pos  = (const float*)d_in[1];
    const float* zero = (const float*)d_in[2];
    const float* neg  = (const float*)d_in[3];
    float* out = (float*)d_out;

    unsigned short* xT = (unsigned short*)d_ws;                       // 32 MiB
    float4* Vt = (float4*)((char*)d_ws + (size_t)32 * 1024 * 1024);   // 128 KiB

    prep<<<dim3(4097), 512, 0, stream>>>(x, pos, zero, neg, xT, Vt);
    fft_conv<<<dim3(NB * 256), 1024, 0, stream>>>(xT, Vt);
    untranspose<<<dim3(64, 8, 8), 256, 0, stream>>>(xT, out);
}

// Round 22
// 97.956 us; speedup vs baseline: 1.4696x; 1.4696x over previous
//
#include <hip/hip_runtime.h>
#include <hip/hip_bf16.h>
#include <stdint.h>

#define NSEQ 4096
#define DDIM 512
#define NB   8
#define FN   8192          // FFT length = 2*NSEQ

#define PADI(i) ((i) + ((i) >> 4))

struct __align__(8) cf { float x, y; };

__device__ __forceinline__ cf cadd(cf a, cf b) { return {a.x + b.x, a.y + b.y}; }
__device__ __forceinline__ cf csub(cf a, cf b) { return {a.x - b.x, a.y - b.y}; }
__device__ __forceinline__ cf cmul(cf a, cf b) {
    return {a.x * b.x - a.y * b.y, a.x * b.y + a.y * b.x};
}
__device__ __forceinline__ cf cmulc(cf a, cf b) {   // a * conj(b)
    return {a.x * b.x + a.y * b.y, a.y * b.x - a.x * b.y};
}
template<int DIR> __device__ __forceinline__ cf crot(cf z) {  // *(-i) fwd, *(+i) inv
    return DIR < 0 ? cf{z.y, -z.x} : cf{-z.y, z.x};
}

__device__ __forceinline__ unsigned short f2bf(float f) {
    union { float f; unsigned int u; } v;
    v.f = f;
    unsigned int u = v.u;
    u += 0x7FFFu + ((u >> 16) & 1u);   // RNE
    return (unsigned short)(u >> 16);
}
__device__ __forceinline__ float bf2f(unsigned short u) {
    union { unsigned int i; float f; } v;
    v.i = (unsigned int)u << 16;
    return v.f;
}

// ---------------------------------------------------------------------------
// 8-point DFT pieces
// ---------------------------------------------------------------------------
template<int DIR>
__device__ __forceinline__ void fft4(cf& b0, cf& b1, cf& b2, cf& b3) {
    cf s0 = cadd(b0, b2), s1 = csub(b0, b2);
    cf s2 = cadd(b1, b3), s3 = crot<DIR>(csub(b1, b3));
    b0 = cadd(s0, s2); b1 = cadd(s1, s3);
    b2 = csub(s0, s2); b3 = csub(s1, s3);
}

template<int DIR>
__device__ __forceinline__ void dft8(cf a[8]) {
    cf e0 = a[0], e1 = a[2], e2 = a[4], e3 = a[6];
    cf o0 = a[1], o1 = a[3], o2 = a[5], o3 = a[7];
    fft4<DIR>(e0, e1, e2, e3);
    fft4<DIR>(o0, o1, o2, o3);
    const float c = 0.70710678118654752f;
    cf w1 = (DIR < 0) ? cf{c, -c} : cf{c, c};
    cf w3 = (DIR < 0) ? cf{-c, -c} : cf{-c, c};
    o1 = cmul(o1, w1);
    o2 = crot<DIR>(o2);
    o3 = cmul(o3, w3);
    a[0] = cadd(e0, o0); a[1] = cadd(e1, o1); a[2] = cadd(e2, o2); a[3] = cadd(e3, o3);
    a[4] = csub(e0, o0); a[5] = csub(e1, o1); a[6] = csub(e2, o2); a[7] = csub(e3, o3);
}

// DFT8 with a[4..7] == 0 (zero-padded upper half), inputs a0..a3
template<int DIR>
__device__ __forceinline__ void dft8_half(cf a0, cf a1, cf a2, cf a3, cf a[8]) {
    cf r2 = crot<DIR>(a2), r3 = crot<DIR>(a3);
    cf e0 = cadd(a0, a2), e1 = cadd(a0, r2), e2 = csub(a0, a2), e3 = csub(a0, r2);
    cf o0 = cadd(a1, a3), o1 = cadd(a1, r3), o2 = csub(a1, a3), o3 = csub(a1, r3);
    const float c = 0.70710678118654752f;
    cf w1 = (DIR < 0) ? cf{c, -c} : cf{c, c};
    cf w3 = (DIR < 0) ? cf{-c, -c} : cf{-c, c};
    o1 = cmul(o1, w1);
    o2 = crot<DIR>(o2);
    o3 = cmul(o3, w3);
    a[0] = cadd(e0, o0); a[1] = cadd(e1, o1); a[2] = cadd(e2, o2); a[3] = cadd(e3, o3);
    a[4] = csub(e0, o0); a[5] = csub(e1, o1); a[6] = csub(e2, o2); a[7] = csub(e3, o3);
}

// depth-3 twiddle powers w[k] = w1^k, k=1..7
__device__ __forceinline__ void twpow(cf w1, cf w[8]) {
    w[1] = w1;
    w[2] = cmul(w1, w1);
    w[3] = cmul(w[2], w1);
    w[4] = cmul(w[2], w[2]);
    w[5] = cmul(w[4], w1);
    w[6] = cmul(w[4], w[2]);
    w[7] = cmul(w[4], w[3]);
}

// ---------------------------------------------------------------------------
// radix-8 stage with LDS power table W7[t8*7+k-1] = w(8*t8)^k.
// fwd: dft8 then *w^k ; inv: *conj(w^k) then dft8.
// ---------------------------------------------------------------------------
template<int DIR, int LM, int TMUL>
__device__ __forceinline__ void r8_stage_tab(cf* Z, const cf* W7, int tid) {
    const int m = 1 << LM;
#pragma unroll
    for (int q = 0; q < 2; ++q) {
        int beta = q * 512 + tid;
        int j = beta & (m - 1);
        int g = beta >> LM;
        int base = (g << (LM + 3)) + j;
        cf a[8];
#pragma unroll
        for (int r = 0; r < 8; ++r) a[r] = Z[PADI(base + (r << LM))];
        cf w[8];
#pragma unroll
        for (int k = 1; k < 8; ++k) w[k] = W7[j * TMUL + k - 1];
        if (DIR > 0) {
#pragma unroll
            for (int k = 1; k < 8; ++k) a[k] = cmulc(a[k], w[k]);
        }
        dft8<DIR>(a);
        if (DIR < 0) {
#pragma unroll
            for (int k = 1; k < 8; ++k) a[k] = cmul(a[k], w[k]);
        }
#pragma unroll
        for (int r = 0; r < 8; ++r) Z[PADI(base + (r << LM))] = a[r];
    }
}

// radix-2 stage on adjacent pairs (build_V only)
template<int NTHR>
__device__ __forceinline__ void r2_stage(cf* Z, int tid) {
#pragma unroll
    for (int q = 0; q < 4096 / NTHR; ++q) {
        int beta = q * NTHR + tid;
        int i0 = PADI(2 * beta), i1 = i0 + 1;
        cf a = Z[i0], b = Z[i1];
        Z[i0] = cadd(a, b);
        Z[i1] = csub(a, b);
    }
}

// sincos-based radix-8 stage (build_V only; runs once)
template<int DIR, int NTHR>
__device__ __forceinline__ void r8_stage(cf* Z, int lm, int tid) {
    const int m = 1 << lm;
    const float ang0 = ((DIR < 0) ? -6.2831853071795865f : 6.2831853071795865f)
                       / (float)(m * 8);
#pragma unroll
    for (int q = 0; q < 1024 / NTHR; ++q) {
        int beta = q * NTHR + tid;
        int j = beta & (m - 1);
        int g = beta >> lm;
        int base = (g << (lm + 3)) + j;
        cf a[8];
#pragma unroll
        for (int r = 0; r < 8; ++r) a[r] = Z[PADI(base + (r << lm))];
        float sn, cs;
        __sincosf(ang0 * (float)j, &sn, &cs);
        cf w[8];
        twpow({cs, sn}, w);
        if (DIR > 0) {
#pragma unroll
            for (int k = 1; k < 8; ++k) a[k] = cmul(a[k], w[k]);
        }
        dft8<DIR>(a);
        if (DIR < 0) {
#pragma unroll
            for (int k = 1; k < 8; ++k) a[k] = cmul(a[k], w[k]);
        }
#pragma unroll
        for (int r = 0; r < 8; ++r) Z[PADI(base + (r << lm))] = a[r];
    }
}

// ---------------------------------------------------------------------------
// Kernel 1 (fused prep): block 0 builds the FOLDED mid-table Vt; blocks
// 1..4096 transpose+convert x -> xT.
// ---------------------------------------------------------------------------
__global__ __launch_bounds__(512) void prep(const float* __restrict__ x,
                                            const float* __restrict__ pos,
                                            const float* __restrict__ zero,
                                            const float* __restrict__ neg,
                                            unsigned short* __restrict__ xT,
                                            float4* __restrict__ Vt4) {
    __shared__ cf Z[PADI(FN)];
    int tid = threadIdx.x;
    if (blockIdx.x == 0) {
        float zv = zero[0];
#pragma unroll
        for (int q = 0; q < 16; ++q) {
            int t = q * 512 + tid;
            float v;
            if (t == 0 || t == NSEQ) v = zv;
            else if (t < NSEQ)       v = pos[t - 1];
            else                     v = neg[t - NSEQ - 1];
            v = fminf(fmaxf(v, -60.0f), 30.0f);
            Z[PADI(t)] = {__expf(v), 0.0f};
        }
        __syncthreads();
        r8_stage<-1, 512>(Z, 10, tid); __syncthreads();
        r8_stage<-1, 512>(Z, 7,  tid); __syncthreads();
        r8_stage<-1, 512>(Z, 4,  tid); __syncthreads();
        r8_stage<-1, 512>(Z, 1,  tid); __syncthreads();
        r2_stage<512>(Z, tid);         __syncthreads();
        const float sc = 1.0f / (float)FN;
#pragma unroll
        for (int q = 0; q < 16; ++q) {
            int i = q * 512 + tid;
            int p = i >> 1, r = p & 7;
            cf V0 = Z[PADI(2 * p)], V1 = Z[PADI(2 * p + 1)];
            cf Vp = {(V0.x + V1.x) * sc, (V0.y + V1.y) * sc};
            cf Vm = {(V0.x - V1.x) * sc, (V0.y - V1.y) * sc};
            float sn, cs;
            __sincosf(-0.39269908169872415f * (float)r, &sn, &cs);
            cf wf = {cs, sn};
            cf B = (i & 1) ? cmulc(Vm, wf) : cmul(Vm, wf);
            Vt4[i] = {Vp.x, Vp.y, B.x, B.y};
        }
    } else {
        unsigned short (*tl)[72] = (unsigned short (*)[72])Z;   // alias LDS
        int t   = blockIdx.x - 1;
        int b   = t >> 9;
        int rem = t & 511;
        int j0  = (rem >> 3) << 6;
        int d0  = (rem & 7) << 6;
        const float* xb = x + (size_t)b * NSEQ * DDIM;
#pragma unroll
        for (int e = 0; e < 2; ++e) {
            int idx = e * 512 + tid;
            int r   = idx >> 4;
            int c4  = (idx & 15) << 2;
            float4 v = *(const float4*)&xb[(size_t)(j0 + r) * DDIM + d0 + c4];
            ushort4 o;
            o.x = f2bf(v.x); o.y = f2bf(v.y); o.z = f2bf(v.z); o.w = f2bf(v.w);
            *(ushort4*)&tl[r][c4] = o;
        }
        __syncthreads();
        unsigned short* xtb = xT + (size_t)b * DDIM * NSEQ;
#pragma unroll
        for (int e = 0; e < 2; ++e) {
            int idx = e * 512 + tid;
            int d   = idx >> 4;
            int jq  = (idx & 15) << 2;
            ushort4 o;
            o.x = tl[jq + 0][d]; o.y = tl[jq + 1][d];
            o.z = tl[jq + 2][d]; o.w = tl[jq + 3][d];
            *(ushort4*)&xtb[(size_t)(d0 + d) * NSEQ + j0 + jq] = o;
        }
    }
}

// ---------------------------------------------------------------------------
// Kernel 2: per column-pair FFT convolution.  512 threads, 2 blocks/CU.
// Wt[512]+KF fixup; W7[128][7] power table; folded-Vt merged pass.
// (r18 configuration — the measured optimum of this structure.)
// ---------------------------------------------------------------------------
__global__ __launch_bounds__(512, 4) void fft_conv(unsigned short* __restrict__ xT,
                                                   const float4* __restrict__ Vt4) {
    __shared__ cf Z[PADI(FN)];
    __shared__ cf Wt[512];
    __shared__ cf W7[896];          // [t8][k-1] = w(8*t8)^k
    int tid = threadIdx.x;
    int blk = blockIdx.x;
    int b   = blk >> 8;
    int dp  = blk & 255;
    unsigned short* col0 = xT + ((size_t)(b * DDIM + 2 * dp)) * NSEQ;
    unsigned short* col1 = col0 + NSEQ;

    // ---- build tables ----
    {
        float sn, cs;
        __sincosf(-7.66990393942820625e-04f * (float)tid, &sn, &cs);  // -2pi t/8192
        Wt[tid] = {cs, sn};
        int e = tid;
        int t8 = e / 7, k = e - t8 * 7 + 1;
        __sincosf(-6.13592315154256492e-03f * (float)(t8 * k), &sn, &cs); // -pi/512*t8*k
        W7[e] = {cs, sn};
        if (tid < 384) {
            e = tid + 512;
            t8 = e / 7; k = e - t8 * 7 + 1;
            __sincosf(-6.13592315154256492e-03f * (float)(t8 * k), &sn, &cs);
            W7[e] = {cs, sn};
        }
    }
    __syncthreads();

    const cf KF = {0.92387953251128674f, -0.38268343236508977f};  // w(512)=e^{-i pi/8}

    // ---- fused load + first forward stage (lm=10, half-zero) ----
#pragma unroll
    for (int q = 0; q < 2; ++q) {
        int j = q * 512 + tid;
        cf a0 = {bf2f(col0[j]),        bf2f(col1[j])};
        cf a1 = {bf2f(col0[j + 1024]), bf2f(col1[j + 1024])};
        cf a2 = {bf2f(col0[j + 2048]), bf2f(col1[j + 2048])};
        cf a3 = {bf2f(col0[j + 3072]), bf2f(col1[j + 3072])};
        cf a[8];
        dft8_half<-1>(a0, a1, a2, a3, a);
        cf w1 = Wt[tid];
        if (q == 1) w1 = cmul(w1, KF);       // compile-time branch per q
        cf w[8];
        twpow(w1, w);
#pragma unroll
        for (int k = 1; k < 8; ++k) a[k] = cmul(a[k], w[k]);
#pragma unroll
        for (int r = 0; r < 8; ++r) Z[PADI(j + (r << 10))] = a[r];
    }
    __syncthreads();

    r8_stage_tab<-1, 7, 7>(Z, W7, tid);   __syncthreads();
    r8_stage_tab<-1, 4, 56>(Z, W7, tid);  __syncthreads();

    // ---- merged: fwd lm=1 + R2 diag(V) R2 + inv lm=1 (twiddles folded) ----
#pragma unroll
    for (int q = 0; q < 2; ++q) {
        const int idx = q * 512 + tid;
        const int g  = idx >> 1;
        const int jj = idx & 1;
        const int base = g * 16 + jj;
        cf a[8];
#pragma unroll
        for (int r = 0; r < 8; ++r) a[r] = Z[PADI(base + 2 * r)];
        dft8<-1>(a);
#pragma unroll
        for (int r = 0; r < 8; ++r) {
            cf own = a[r];
            cf oth;
            oth.x = __shfl_xor(own.x, 1);
            oth.y = __shfl_xor(own.y, 1);
            float4 v = Vt4[base + 2 * r];
            a[r] = cadd(cmul({v.x, v.y}, own), cmul({v.z, v.w}, oth));
        }
        dft8<1>(a);
#pragma unroll
        for (int r = 0; r < 8; ++r) Z[PADI(base + 2 * r)] = a[r];
    }
    __syncthreads();

    r8_stage_tab<1, 4, 56>(Z, W7, tid);   __syncthreads();
    r8_stage_tab<1, 7, 7>(Z, W7, tid);    __syncthreads();

    // ---- fused last inverse stage (lm=10) + store (only idx < 4096) ----
#pragma unroll
    for (int q = 0; q < 2; ++q) {
        int j = q * 512 + tid;
        cf a[8];
#pragma unroll
        for (int r = 0; r < 8; ++r) a[r] = Z[PADI(j + (r << 10))];
        cf w1 = Wt[tid];
        if (q == 1) w1 = cmul(w1, KF);
        w1.y = -w1.y;                       // conjugate for inverse
        cf w[8];
        twpow(w1, w);
#pragma unroll
        for (int k = 1; k < 8; ++k) a[k] = cmul(a[k], w[k]);
        dft8<1>(a);
#pragma unroll
        for (int r = 0; r < 4; ++r) {
            col0[j + (r << 10)] = f2bf(a[r].x);
            col1[j + (r << 10)] = f2bf(a[r].y);
        }
    }
}

// ---------------------------------------------------------------------------
// Kernel 3: un-transpose  out[b][j][d] = f32(outT[b][d][j]).  grid (64,8,8).
// ---------------------------------------------------------------------------
__global__ void untranspose(const unsigned short* __restrict__ oT,
                            float* __restrict__ out) {
    __shared__ unsigned short tl[64][65];
    int j0 = blockIdx.x * 64, d0 = blockIdx.y * 64, b = blockIdx.z;
    const unsigned short* src = oT + (size_t)b * DDIM * NSEQ;
#pragma unroll
    for (int e = 0; e < 16; ++e) {
        int idx = e * 256 + threadIdx.x;
        int r = idx >> 6, c = idx & 63;
        tl[r][c] = src[(size_t)(d0 + r) * NSEQ + j0 + c];
    }
    __syncthreads();
    float* dst = out + ((size_t)b * NSEQ + j0) * DDIM + d0;
#pragma unroll
    for (int e = 0; e < 16; ++e) {
        int idx = e * 256 + threadIdx.x;
        int r = idx >> 6, c = idx & 63;
        dst[(size_t)r * DDIM + c] = bf2f(tl[c][r]);
    }
}

// ---------------------------------------------------------------------------
extern "C" void kernel_launch(void* const* d_in, const int* in_sizes, int n_in,
                              void* d_out, int out_size, void* d_ws, size_t ws_size,
                              hipStream_t stream) {
    const float* x    = (const float*)d_in[0];
    const float* pos  = (const float*)d_in[1];
    const float* zero = (const float*)d_in[2];
    const float* neg  = (const float*)d_in[3];
    float* out = (float*)d_out;

    unsigned short* xT = (unsigned short*)d_ws;                       // 32 MiB
    float4* Vt = (float4*)((char*)d_ws + (size_t)32 * 1024 * 1024);   // 128 KiB

    prep<<<dim3(4097), 512, 0, stream>>>(x, pos, zero, neg, xT, Vt);
    fft_conv<<<dim3(NB * 256), 512, 0, stream>>>(xT, Vt);
    untranspose<<<dim3(64, 8, 8), 256, 0, stream>>>(xT, out);
}